// Round 13
// baseline (282.908 us; speedup 1.0000x reference)
//
#include <hip/hip_runtime.h>
#include <hip/hip_fp16.h>
#include <math.h>

#define NUM_TREES 20000
#define MAX_DEPTH 8
#define MAX_SIZE  40
#define VOCAB     30000
#define DIM       128
#define TOT       (MAX_DEPTH * MAX_SIZE)       // 320 tokens per tree
#define NTILE     8
#define TILE_ROWS (VOCAB / NTILE)              // 3750 rows
#define TPA       4                            // trees per block (wave per tree)

typedef unsigned long long ull;

__device__ __forceinline__ double waveSumD(double v) {
    v += __shfl_xor(v, 32);
    v += __shfl_xor(v, 16);
    v += __shfl_xor(v, 8);
    v += __shfl_xor(v, 4);
    v += __shfl_xor(v, 2);
    v += __shfl_xor(v, 1);
    return v;
}

__device__ __forceinline__ float waveSumF(float v) {
    v += __shfl_xor(v, 32);
    v += __shfl_xor(v, 16);
    v += __shfl_xor(v, 8);
    v += __shfl_xor(v, 4);
    v += __shfl_xor(v, 2);
    v += __shfl_xor(v, 1);
    return v;
}

// One packed butterfly for three independent fp32 sums (ILP hides the
// per-step shuffle latency across the three chains).
__device__ __forceinline__ void waveSum3F(float& a, float& b, float& c) {
    #pragma unroll
    for (int m = 32; m >= 1; m >>= 1) {
        a += __shfl_xor(a, m);
        b += __shfl_xor(b, m);
        c += __shfl_xor(c, m);
    }
}

// masks may arrive as 1-byte bool or int32; probe word 0 (all-ones input:
// byte layout reads 0x01010101, int32 layout reads 0x00000001).
__device__ __forceinline__ int loadMask(const void* m, size_t idx, bool asByte) {
    return asByte ? (int)((const unsigned char*)m)[idx] : ((const int*)m)[idx];
}

// Phase 0 (fused): ts[v] = dot(embedding[v], cw) (fp64 reduce, f32 store)
// AND fp16 conversion of the row the wave already holds.
__global__ __launch_bounds__(256) void tokscore_kernel(
        const float* __restrict__ emb, const float* __restrict__ cw,
        float* __restrict__ ts, __half2* __restrict__ e16) {
    int row  = (blockIdx.x * blockDim.x + threadIdx.x) >> 6;
    int lane = threadIdx.x & 63;
    if (row >= VOCAB) return;
    float2 e2 = *(const float2*)(emb + (size_t)row * DIM + lane * 2);
    float2 w2 = *(const float2*)(cw + lane * 2);
    if (e16) e16[(size_t)row * 64 + lane] = __floats2half2_rn(e2.x, e2.y);
    double p = (double)e2.x * (double)w2.x + (double)e2.y * (double)w2.y;
    p = waveSumD(p);
    if (lane == 0) ts[row] = (float)p;
}

// Shared device body: fp32 recursion + ballot sort (validated round 12;
// absmax unchanged at 0.0078 — fp16 table dominates the error).
__device__ __forceinline__ int recursion_and_sort(
        const int* __restrict__ tokens, const void* __restrict__ masks,
        const float* __restrict__ ts, ull (*l_pair)[TOT],
        int w, int s, size_t base) {
    const bool mByte = (((const int*)masks)[0] != 1);
    const bool inS = s < MAX_SIZE;

    int   tok[MAX_DEPTH];
    float e[MAX_DEPTH];
    unsigned int valbit = 0, mskbit = 0;
    #pragma unroll
    for (int d = 0; d < MAX_DEPTH; ++d) {
        int t = -1, m = 0;
        if (inS) {
            t = tokens[base + d * MAX_SIZE + s];
            m = loadMask(masks, base + d * MAX_SIZE + s, mByte);
        }
        tok[d] = t < 0 ? 0 : t;
        e[d]   = inS ? ts[tok[d]] : 0.0f;
        if (inS && m != 0) mskbit |= 1u << d;
        if (inS && m != 0 && t >= 0) valbit |= 1u << d;
    }
    unsigned int childbit = 0;
    #pragma unroll
    for (int d = 0; d < MAX_DEPTH - 1; ++d) {
        ull bal = __ballot((mskbit >> (d + 1)) & 1u);
        int nc = (int)__popcll(bal);
        if (nc < 1) nc = 1;
        if (((valbit >> d) & 1u) && s < nc) childbit |= 1u << d;
    }

    float v7 = ((valbit >> 7) & 1u) ? 1.0f : 0.0f;
    float pw = waveSumF(e[7] * v7);

    float attnf[MAX_DEPTH - 1];
    float cArr[MAX_DEPTH - 1];
    #pragma unroll
    for (int d = MAX_DEPTH - 2; d >= 0; --d) {
        float gf = 1.0f / (1.0f + __expf(-e[d]));
        float cf = ((childbit >> d) & 1u) ? gf : 0.0f;   // gate*child
        float a  = fmaf(cf, pw, e[d]);
        float ex = ((valbit >> d) & 1u) ? __expf(a) : 0.0f;
        float s0 = ex;            // -> den
        float s1 = ex * cf;       // -> c * den
        float s2 = ex * e[d];     // -> (sum attn*e) * den
        waveSum3F(s0, s1, s2);
        float inv = 1.0f / s0;
        float c   = s1 * inv;
        pw = fmaf(c, pw, s2 * inv);
        attnf[d] = ex * inv;      // attn
        cArr[d]  = c;
    }
    float coef[MAX_DEPTH];
    float prefix = 1.0f;
    #pragma unroll
    for (int d = 0; d <= MAX_DEPTH - 2; ++d) {
        coef[d] = prefix * attnf[d];
        prefix *= cArr[d];
    }
    coef[MAX_DEPTH - 1] = prefix * v7;

    int tl[MAX_DEPTH];
    unsigned int nzbit = 0;
    #pragma unroll
    for (int d = 0; d < MAX_DEPTH; ++d) {
        tl[d] = tok[d] / TILE_ROWS;
        if (coef[d] != 0.0f) nzbit |= 1u << d;
    }
    const ull ltm = (1ull << s) - 1ull;

    int cnt[NTILE];
    #pragma unroll
    for (int t = 0; t < NTILE; ++t) cnt[t] = 0;
    #pragma unroll
    for (int d = 0; d < MAX_DEPTH; ++d) {
        bool nz = (nzbit >> d) & 1u;
        #pragma unroll
        for (int t = 0; t < NTILE; ++t)
            cnt[t] += (int)__popcll(__ballot(nz && tl[d] == t));
    }
    int hoff[NTILE + 1];
    hoff[0] = 0;
    #pragma unroll
    for (int t = 0; t < NTILE; ++t) hoff[t + 1] = hoff[t] + cnt[t];

    int ridx[NTILE];
    #pragma unroll
    for (int t = 0; t < NTILE; ++t) ridx[t] = hoff[t];
    #pragma unroll
    for (int d = 0; d < MAX_DEPTH; ++d) {
        bool nz = (nzbit >> d) & 1u;
        int slot = -1;
        #pragma unroll
        for (int t = 0; t < NTILE; ++t) {
            ull m = __ballot(nz && tl[d] == t);
            if (nz && tl[d] == t) slot = ridx[t] + (int)__popcll(m & ltm);
            ridx[t] += (int)__popcll(m);
        }
        if (slot >= 0)
            l_pair[w][slot] =
                ((ull)__float_as_uint(coef[d]) << 32) | (ull)(unsigned)tok[d];
    }
    return __builtin_amdgcn_readfirstlane(hoff[NTILE]);
}

// Fused kernel, fp16 quarter-wave gather (validated rounds 11-12).
// ROUND 13 CHANGE: __launch_bounds__(256, 8). Evidence: every (256,4) round
// pegs at 49-53% occupancy (= exactly 4 waves/EU) while round 9's (256,8)
// hit 83% — the 2nd arg acts as an occupancy cap, not just a VGPR promise.
// Round 9 spilled because the fp64 recursion couldn't fit the implied
// <=64-VGPR budget; the fp32 recursion measures 44 VGPR unconstrained, so
// it fits with 20 regs of headroom. 2x waves = 2x in-flight gather bytes
// (the proven scaling lever from rounds 10-11) + 2x shuffle-latency hiding.
__global__ __launch_bounds__(256, 8) void fused16_kernel(
        const int* __restrict__ tokens, const void* __restrict__ masks,
        const float* __restrict__ ts, const __half* __restrict__ e16,
        float* __restrict__ out) {
    __shared__ ull l_pair[TPA][TOT];   // 10 KB, tile-sorted pairs per tree

    const int tid  = threadIdx.x;
    const int w    = tid >> 6;
    const int s    = tid & 63;
    const int tree = blockIdx.x * TPA + w;
    const size_t base = (size_t)tree * TOT;

    const int nTot = recursion_and_sort(tokens, masks, ts, l_pair, w, s, base);

    // Gather (wave-local LDS, no barrier needed — validated rounds 5-12).
    const int q  = s >> 4;                 // quarter id: row offset 0..3
    const int cb = (s & 15) << 3;          // column base: 8 elements per lane
    const ull* lp = &l_pair[w][0];
    float a0 = 0.f, a1 = 0.f, a2 = 0.f, a3 = 0.f;
    float a4 = 0.f, a5 = 0.f, a6 = 0.f, a7 = 0.f;

    int j = 0;
    for (; j + 32 <= nTot; j += 32) {      // 32 rows = 8 uint4 loads in flight
        ull pr[8];
        #pragma unroll
        for (int k = 0; k < 8; ++k) pr[k] = lp[j + 4 * k + q];
        uint4 v[8];
        #pragma unroll
        for (int k = 0; k < 8; ++k)
            v[k] = *(const uint4*)(e16 + (size_t)(unsigned)pr[k] * DIM + cb);
        __builtin_amdgcn_sched_barrier(0);  // all 8 loads issued before use
        #pragma unroll
        for (int k = 0; k < 8; ++k) {
            float wt = __uint_as_float((unsigned)(pr[k] >> 32));
            float2 f0 = __half22float2(*(const __half2*)&v[k].x);
            float2 f1 = __half22float2(*(const __half2*)&v[k].y);
            float2 f2 = __half22float2(*(const __half2*)&v[k].z);
            float2 f3 = __half22float2(*(const __half2*)&v[k].w);
            a0 = fmaf(wt, f0.x, a0); a1 = fmaf(wt, f0.y, a1);
            a2 = fmaf(wt, f1.x, a2); a3 = fmaf(wt, f1.y, a3);
            a4 = fmaf(wt, f2.x, a4); a5 = fmaf(wt, f2.y, a5);
            a6 = fmaf(wt, f3.x, a6); a7 = fmaf(wt, f3.y, a7);
        }
    }
    for (; j + 4 <= nTot; j += 4) {        // 4 rows per step
        ull pr = lp[j + q];
        float wt = __uint_as_float((unsigned)(pr >> 32));
        uint4 v = *(const uint4*)(e16 + (size_t)(unsigned)pr * DIM + cb);
        float2 f0 = __half22float2(*(const __half2*)&v.x);
        float2 f1 = __half22float2(*(const __half2*)&v.y);
        float2 f2 = __half22float2(*(const __half2*)&v.z);
        float2 f3 = __half22float2(*(const __half2*)&v.w);
        a0 = fmaf(wt, f0.x, a0); a1 = fmaf(wt, f0.y, a1);
        a2 = fmaf(wt, f1.x, a2); a3 = fmaf(wt, f1.y, a3);
        a4 = fmaf(wt, f2.x, a4); a5 = fmaf(wt, f2.y, a5);
        a6 = fmaf(wt, f3.x, a6); a7 = fmaf(wt, f3.y, a7);
    }
    if (j < nTot) {                        // 1-3 leftover rows
        int rem = nTot - j;
        ull pr = lp[j + (q < rem ? q : 0)];            // inactive quarters re-
        float wt = (q < rem) ? __uint_as_float((unsigned)(pr >> 32)) : 0.0f;
        uint4 v = *(const uint4*)(e16 + (size_t)(unsigned)pr * DIM + cb);
        float2 f0 = __half22float2(*(const __half2*)&v.x); // read row j, wt=0
        float2 f1 = __half22float2(*(const __half2*)&v.y);
        float2 f2 = __half22float2(*(const __half2*)&v.z);
        float2 f3 = __half22float2(*(const __half2*)&v.w);
        a0 = fmaf(wt, f0.x, a0); a1 = fmaf(wt, f0.y, a1);
        a2 = fmaf(wt, f1.x, a2); a3 = fmaf(wt, f1.y, a3);
        a4 = fmaf(wt, f2.x, a4); a5 = fmaf(wt, f2.y, a5);
        a6 = fmaf(wt, f3.x, a6); a7 = fmaf(wt, f3.y, a7);
    }

    // Reduce across the 4 quarters (lanes with equal (s&15) share columns).
    a0 += __shfl_xor(a0, 16); a1 += __shfl_xor(a1, 16);
    a2 += __shfl_xor(a2, 16); a3 += __shfl_xor(a3, 16);
    a4 += __shfl_xor(a4, 16); a5 += __shfl_xor(a5, 16);
    a6 += __shfl_xor(a6, 16); a7 += __shfl_xor(a7, 16);
    a0 += __shfl_xor(a0, 32); a1 += __shfl_xor(a1, 32);
    a2 += __shfl_xor(a2, 32); a3 += __shfl_xor(a3, 32);
    a4 += __shfl_xor(a4, 32); a5 += __shfl_xor(a5, 32);
    a6 += __shfl_xor(a6, 32); a7 += __shfl_xor(a7, 32);

    if (s < 16) {
        float* op = out + (size_t)tree * DIM + cb;
        *(float4*)op       = make_float4(a0, a1, a2, a3);
        *(float4*)(op + 4) = make_float4(a4, a5, a6, a7);
    }
}

// Fallback: fp32-table fused gather (validated rounds 7-8) for tiny
// workspaces.
__global__ __launch_bounds__(256, 4) void fused_kernel(
        const int* __restrict__ tokens, const void* __restrict__ masks,
        const float* __restrict__ ts, const float* __restrict__ emb,
        float* __restrict__ out) {
    __shared__ ull l_pair[TPA][TOT];

    const int tid  = threadIdx.x;
    const int w    = tid >> 6;
    const int s    = tid & 63;
    const int tree = blockIdx.x * TPA + w;
    const size_t base = (size_t)tree * TOT;

    const int nTot = recursion_and_sort(tokens, masks, ts, l_pair, w, s, base);

    const int hi = (s >= 32) ? 1 : 0;
    const int cb = (s & 31) << 2;
    const ull* lp = &l_pair[w][0];
    float a0 = 0.0f, a1 = 0.0f, a2 = 0.0f, a3 = 0.0f;

    int j = 0;
    for (; j + 8 <= nTot; j += 8) {
        ull pr[4];
        #pragma unroll
        for (int k = 0; k < 4; ++k) pr[k] = lp[j + 2 * k + hi];
        float4 v[4];
        #pragma unroll
        for (int k = 0; k < 4; ++k)
            v[k] = *(const float4*)(emb + (size_t)(unsigned)pr[k] * DIM + cb);
        #pragma unroll
        for (int k = 0; k < 4; ++k) {
            float wt = __uint_as_float((unsigned)(pr[k] >> 32));
            a0 = fmaf(wt, v[k].x, a0); a1 = fmaf(wt, v[k].y, a1);
            a2 = fmaf(wt, v[k].z, a2); a3 = fmaf(wt, v[k].w, a3);
        }
    }
    for (; j + 2 <= nTot; j += 2) {
        ull pr = lp[j + hi];
        float wt = __uint_as_float((unsigned)(pr >> 32));
        const float4 v = *(const float4*)(emb + (size_t)(unsigned)pr * DIM + cb);
        a0 = fmaf(wt, v.x, a0); a1 = fmaf(wt, v.y, a1);
        a2 = fmaf(wt, v.z, a2); a3 = fmaf(wt, v.w, a3);
    }
    if (j < nTot) {
        ull pr = lp[j];
        float wt = hi ? 0.0f : __uint_as_float((unsigned)(pr >> 32));
        const float4 v = *(const float4*)(emb + (size_t)(unsigned)pr * DIM + cb);
        a0 = fmaf(wt, v.x, a0); a1 = fmaf(wt, v.y, a1);
        a2 = fmaf(wt, v.z, a2); a3 = fmaf(wt, v.w, a3);
    }

    a0 += __shfl_xor(a0, 32);
    a1 += __shfl_xor(a1, 32);
    a2 += __shfl_xor(a2, 32);
    a3 += __shfl_xor(a3, 32);

    if (s < 32) {
        float* op = out + (size_t)tree * DIM + cb;
        *(float4*)op = make_float4(a0, a1, a2, a3);
    }
}

extern "C" void kernel_launch(void* const* d_in, const int* in_sizes, int n_in,
                              void* d_out, int out_size, void* d_ws, size_t ws_size,
                              hipStream_t stream) {
    const int*   tokens = (const int*)d_in[0];
    const void*  masks  = d_in[1];
    const float* emb    = (const float*)d_in[2];
    const float* cw     = (const float*)d_in[3];
    float*       out    = (float*)d_out;

    // Workspace: ts f32 (120 KB, padded to 128 KB) + fp16 table (7.68 MB).
    const size_t o_ts  = 0;
    const size_t o_e16 = 128 * 1024;
    const size_t need  = o_e16 + (size_t)VOCAB * DIM * 2;

    float*  ts  = (float*)((char*)d_ws + o_ts);
    __half* e16 = (__half*)((char*)d_ws + o_e16);

    const bool fp16path = (ws_size >= need);
    int ts_blocks = (VOCAB * 64 + 255) / 256;   // one wave per vocab row
    tokscore_kernel<<<ts_blocks, 256, 0, stream>>>(
        emb, cw, ts, fp16path ? (__half2*)e16 : (__half2*)nullptr);

    if (fp16path) {
        fused16_kernel<<<NUM_TREES / TPA, 256, 0, stream>>>(tokens, masks, ts,
                                                            e16, out);
    } else {
        fused_kernel<<<NUM_TREES / TPA, 256, 0, stream>>>(tokens, masks, ts,
                                                          emb, out);
    }
}

// Round 14
// 239.261 us; speedup vs baseline: 1.1824x; 1.1824x over previous
//
#include <hip/hip_runtime.h>
#include <hip/hip_fp16.h>
#include <math.h>

#define NUM_TREES 20000
#define MAX_DEPTH 8
#define MAX_SIZE  40
#define VOCAB     30000
#define DIM       128
#define TOT       (MAX_DEPTH * MAX_SIZE)       // 320 tokens per tree
#define NTILE     8
#define TILE_ROWS (VOCAB / NTILE)              // 3750 rows
#define TPA       4                            // trees per block (wave per tree)

typedef unsigned long long ull;

__device__ __forceinline__ double waveSumD(double v) {
    v += __shfl_xor(v, 32);
    v += __shfl_xor(v, 16);
    v += __shfl_xor(v, 8);
    v += __shfl_xor(v, 4);
    v += __shfl_xor(v, 2);
    v += __shfl_xor(v, 1);
    return v;
}

__device__ __forceinline__ float waveSumF(float v) {
    v += __shfl_xor(v, 32);
    v += __shfl_xor(v, 16);
    v += __shfl_xor(v, 8);
    v += __shfl_xor(v, 4);
    v += __shfl_xor(v, 2);
    v += __shfl_xor(v, 1);
    return v;
}

// One packed butterfly for three independent fp32 sums (ILP hides the
// per-step shuffle latency across the three chains).
__device__ __forceinline__ void waveSum3F(float& a, float& b, float& c) {
    #pragma unroll
    for (int m = 32; m >= 1; m >>= 1) {
        a += __shfl_xor(a, m);
        b += __shfl_xor(b, m);
        c += __shfl_xor(c, m);
    }
}

// masks may arrive as 1-byte bool or int32; probe word 0 (all-ones input:
// byte layout reads 0x01010101, int32 layout reads 0x00000001).
__device__ __forceinline__ int loadMask(const void* m, size_t idx, bool asByte) {
    return asByte ? (int)((const unsigned char*)m)[idx] : ((const int*)m)[idx];
}

// Phase 0 (fused): ts[v] = dot(embedding[v], cw) (fp64 reduce, f32 store)
// AND fp16 conversion of the row the wave already holds.
__global__ __launch_bounds__(256) void tokscore_kernel(
        const float* __restrict__ emb, const float* __restrict__ cw,
        float* __restrict__ ts, __half2* __restrict__ e16) {
    int row  = (blockIdx.x * blockDim.x + threadIdx.x) >> 6;
    int lane = threadIdx.x & 63;
    if (row >= VOCAB) return;
    float2 e2 = *(const float2*)(emb + (size_t)row * DIM + lane * 2);
    float2 w2 = *(const float2*)(cw + lane * 2);
    if (e16) e16[(size_t)row * 64 + lane] = __floats2half2_rn(e2.x, e2.y);
    double p = (double)e2.x * (double)w2.x + (double)e2.y * (double)w2.y;
    p = waveSumD(p);
    if (lane == 0) ts[row] = (float)p;
}

// Shared device body: fp32 recursion + ballot sort (validated round 12;
// absmax unchanged at 0.0078 — fp16 table dominates the error).
__device__ __forceinline__ int recursion_and_sort(
        const int* __restrict__ tokens, const void* __restrict__ masks,
        const float* __restrict__ ts, ull (*l_pair)[TOT],
        int w, int s, size_t base) {
    const bool mByte = (((const int*)masks)[0] != 1);
    const bool inS = s < MAX_SIZE;

    int   tok[MAX_DEPTH];
    float e[MAX_DEPTH];
    unsigned int valbit = 0, mskbit = 0;
    #pragma unroll
    for (int d = 0; d < MAX_DEPTH; ++d) {
        int t = -1, m = 0;
        if (inS) {
            t = tokens[base + d * MAX_SIZE + s];
            m = loadMask(masks, base + d * MAX_SIZE + s, mByte);
        }
        tok[d] = t < 0 ? 0 : t;
        e[d]   = inS ? ts[tok[d]] : 0.0f;
        if (inS && m != 0) mskbit |= 1u << d;
        if (inS && m != 0 && t >= 0) valbit |= 1u << d;
    }
    unsigned int childbit = 0;
    #pragma unroll
    for (int d = 0; d < MAX_DEPTH - 1; ++d) {
        ull bal = __ballot((mskbit >> (d + 1)) & 1u);
        int nc = (int)__popcll(bal);
        if (nc < 1) nc = 1;
        if (((valbit >> d) & 1u) && s < nc) childbit |= 1u << d;
    }

    float v7 = ((valbit >> 7) & 1u) ? 1.0f : 0.0f;
    float pw = waveSumF(e[7] * v7);

    float attnf[MAX_DEPTH - 1];
    float cArr[MAX_DEPTH - 1];
    #pragma unroll
    for (int d = MAX_DEPTH - 2; d >= 0; --d) {
        float gf = 1.0f / (1.0f + __expf(-e[d]));
        float cf = ((childbit >> d) & 1u) ? gf : 0.0f;   // gate*child
        float a  = fmaf(cf, pw, e[d]);
        float ex = ((valbit >> d) & 1u) ? __expf(a) : 0.0f;
        float s0 = ex;            // -> den
        float s1 = ex * cf;       // -> c * den
        float s2 = ex * e[d];     // -> (sum attn*e) * den
        waveSum3F(s0, s1, s2);
        float inv = 1.0f / s0;
        float c   = s1 * inv;
        pw = fmaf(c, pw, s2 * inv);
        attnf[d] = ex * inv;      // attn
        cArr[d]  = c;
    }
    float coef[MAX_DEPTH];
    float prefix = 1.0f;
    #pragma unroll
    for (int d = 0; d <= MAX_DEPTH - 2; ++d) {
        coef[d] = prefix * attnf[d];
        prefix *= cArr[d];
    }
    coef[MAX_DEPTH - 1] = prefix * v7;

    int tl[MAX_DEPTH];
    unsigned int nzbit = 0;
    #pragma unroll
    for (int d = 0; d < MAX_DEPTH; ++d) {
        tl[d] = tok[d] / TILE_ROWS;
        if (coef[d] != 0.0f) nzbit |= 1u << d;
    }
    const ull ltm = (1ull << s) - 1ull;

    int cnt[NTILE];
    #pragma unroll
    for (int t = 0; t < NTILE; ++t) cnt[t] = 0;
    #pragma unroll
    for (int d = 0; d < MAX_DEPTH; ++d) {
        bool nz = (nzbit >> d) & 1u;
        #pragma unroll
        for (int t = 0; t < NTILE; ++t)
            cnt[t] += (int)__popcll(__ballot(nz && tl[d] == t));
    }
    int hoff[NTILE + 1];
    hoff[0] = 0;
    #pragma unroll
    for (int t = 0; t < NTILE; ++t) hoff[t + 1] = hoff[t] + cnt[t];

    int ridx[NTILE];
    #pragma unroll
    for (int t = 0; t < NTILE; ++t) ridx[t] = hoff[t];
    #pragma unroll
    for (int d = 0; d < MAX_DEPTH; ++d) {
        bool nz = (nzbit >> d) & 1u;
        int slot = -1;
        #pragma unroll
        for (int t = 0; t < NTILE; ++t) {
            ull m = __ballot(nz && tl[d] == t);
            if (nz && tl[d] == t) slot = ridx[t] + (int)__popcll(m & ltm);
            ridx[t] += (int)__popcll(m);
        }
        if (slot >= 0)
            l_pair[w][slot] =
                ((ull)__float_as_uint(coef[d]) << 32) | (ull)(unsigned)tok[d];
    }
    return __builtin_amdgcn_readfirstlane(hoff[NTILE]);
}

// Fused kernel, fp16 quarter-wave gather (validated rounds 11-12).
// ROUND 14 CHANGE: __launch_bounds__(256, 5). Empirical hipcc mapping of the
// 2nd arg to a per-wave VGPR cap is ~256/N (not 512/N): (256,4)->64 [no
// spill, 50% occ], (256,6)->~42 [round 6 spill], (256,8)->32 [rounds 9/13
// spill]. The fp32 kernel needs 44 VGPR naturally; (256,5)'s ~51 cap is the
// only point that adds waves (5/EU = 62.5% occ) while still fitting 44.
__global__ __launch_bounds__(256, 5) void fused16_kernel(
        const int* __restrict__ tokens, const void* __restrict__ masks,
        const float* __restrict__ ts, const __half* __restrict__ e16,
        float* __restrict__ out) {
    __shared__ ull l_pair[TPA][TOT];   // 10 KB, tile-sorted pairs per tree

    const int tid  = threadIdx.x;
    const int w    = tid >> 6;
    const int s    = tid & 63;
    const int tree = blockIdx.x * TPA + w;
    const size_t base = (size_t)tree * TOT;

    const int nTot = recursion_and_sort(tokens, masks, ts, l_pair, w, s, base);

    // Gather (wave-local LDS, no barrier needed — validated rounds 5-13).
    const int q  = s >> 4;                 // quarter id: row offset 0..3
    const int cb = (s & 15) << 3;          // column base: 8 elements per lane
    const ull* lp = &l_pair[w][0];
    float a0 = 0.f, a1 = 0.f, a2 = 0.f, a3 = 0.f;
    float a4 = 0.f, a5 = 0.f, a6 = 0.f, a7 = 0.f;

    int j = 0;
    for (; j + 32 <= nTot; j += 32) {      // 32 rows = 8 uint4 loads in flight
        ull pr[8];
        #pragma unroll
        for (int k = 0; k < 8; ++k) pr[k] = lp[j + 4 * k + q];
        uint4 v[8];
        #pragma unroll
        for (int k = 0; k < 8; ++k)
            v[k] = *(const uint4*)(e16 + (size_t)(unsigned)pr[k] * DIM + cb);
        __builtin_amdgcn_sched_barrier(0);  // all 8 loads issued before use
        #pragma unroll
        for (int k = 0; k < 8; ++k) {
            float wt = __uint_as_float((unsigned)(pr[k] >> 32));
            float2 f0 = __half22float2(*(const __half2*)&v[k].x);
            float2 f1 = __half22float2(*(const __half2*)&v[k].y);
            float2 f2 = __half22float2(*(const __half2*)&v[k].z);
            float2 f3 = __half22float2(*(const __half2*)&v[k].w);
            a0 = fmaf(wt, f0.x, a0); a1 = fmaf(wt, f0.y, a1);
            a2 = fmaf(wt, f1.x, a2); a3 = fmaf(wt, f1.y, a3);
            a4 = fmaf(wt, f2.x, a4); a5 = fmaf(wt, f2.y, a5);
            a6 = fmaf(wt, f3.x, a6); a7 = fmaf(wt, f3.y, a7);
        }
    }
    for (; j + 4 <= nTot; j += 4) {        // 4 rows per step
        ull pr = lp[j + q];
        float wt = __uint_as_float((unsigned)(pr >> 32));
        uint4 v = *(const uint4*)(e16 + (size_t)(unsigned)pr * DIM + cb);
        float2 f0 = __half22float2(*(const __half2*)&v.x);
        float2 f1 = __half22float2(*(const __half2*)&v.y);
        float2 f2 = __half22float2(*(const __half2*)&v.z);
        float2 f3 = __half22float2(*(const __half2*)&v.w);
        a0 = fmaf(wt, f0.x, a0); a1 = fmaf(wt, f0.y, a1);
        a2 = fmaf(wt, f1.x, a2); a3 = fmaf(wt, f1.y, a3);
        a4 = fmaf(wt, f2.x, a4); a5 = fmaf(wt, f2.y, a5);
        a6 = fmaf(wt, f3.x, a6); a7 = fmaf(wt, f3.y, a7);
    }
    if (j < nTot) {                        // 1-3 leftover rows
        int rem = nTot - j;
        ull pr = lp[j + (q < rem ? q : 0)];            // inactive quarters re-
        float wt = (q < rem) ? __uint_as_float((unsigned)(pr >> 32)) : 0.0f;
        uint4 v = *(const uint4*)(e16 + (size_t)(unsigned)pr * DIM + cb);
        float2 f0 = __half22float2(*(const __half2*)&v.x); // read row j, wt=0
        float2 f1 = __half22float2(*(const __half2*)&v.y);
        float2 f2 = __half22float2(*(const __half2*)&v.z);
        float2 f3 = __half22float2(*(const __half2*)&v.w);
        a0 = fmaf(wt, f0.x, a0); a1 = fmaf(wt, f0.y, a1);
        a2 = fmaf(wt, f1.x, a2); a3 = fmaf(wt, f1.y, a3);
        a4 = fmaf(wt, f2.x, a4); a5 = fmaf(wt, f2.y, a5);
        a6 = fmaf(wt, f3.x, a6); a7 = fmaf(wt, f3.y, a7);
    }

    // Reduce across the 4 quarters (lanes with equal (s&15) share columns).
    a0 += __shfl_xor(a0, 16); a1 += __shfl_xor(a1, 16);
    a2 += __shfl_xor(a2, 16); a3 += __shfl_xor(a3, 16);
    a4 += __shfl_xor(a4, 16); a5 += __shfl_xor(a5, 16);
    a6 += __shfl_xor(a6, 16); a7 += __shfl_xor(a7, 16);
    a0 += __shfl_xor(a0, 32); a1 += __shfl_xor(a1, 32);
    a2 += __shfl_xor(a2, 32); a3 += __shfl_xor(a3, 32);
    a4 += __shfl_xor(a4, 32); a5 += __shfl_xor(a5, 32);
    a6 += __shfl_xor(a6, 32); a7 += __shfl_xor(a7, 32);

    if (s < 16) {
        float* op = out + (size_t)tree * DIM + cb;
        *(float4*)op       = make_float4(a0, a1, a2, a3);
        *(float4*)(op + 4) = make_float4(a4, a5, a6, a7);
    }
}

// Fallback: fp32-table fused gather (validated rounds 7-8) for tiny
// workspaces.
__global__ __launch_bounds__(256, 4) void fused_kernel(
        const int* __restrict__ tokens, const void* __restrict__ masks,
        const float* __restrict__ ts, const float* __restrict__ emb,
        float* __restrict__ out) {
    __shared__ ull l_pair[TPA][TOT];

    const int tid  = threadIdx.x;
    const int w    = tid >> 6;
    const int s    = tid & 63;
    const int tree = blockIdx.x * TPA + w;
    const size_t base = (size_t)tree * TOT;

    const int nTot = recursion_and_sort(tokens, masks, ts, l_pair, w, s, base);

    const int hi = (s >= 32) ? 1 : 0;
    const int cb = (s & 31) << 2;
    const ull* lp = &l_pair[w][0];
    float a0 = 0.0f, a1 = 0.0f, a2 = 0.0f, a3 = 0.0f;

    int j = 0;
    for (; j + 8 <= nTot; j += 8) {
        ull pr[4];
        #pragma unroll
        for (int k = 0; k < 4; ++k) pr[k] = lp[j + 2 * k + hi];
        float4 v[4];
        #pragma unroll
        for (int k = 0; k < 4; ++k)
            v[k] = *(const float4*)(emb + (size_t)(unsigned)pr[k] * DIM + cb);
        #pragma unroll
        for (int k = 0; k < 4; ++k) {
            float wt = __uint_as_float((unsigned)(pr[k] >> 32));
            a0 = fmaf(wt, v[k].x, a0); a1 = fmaf(wt, v[k].y, a1);
            a2 = fmaf(wt, v[k].z, a2); a3 = fmaf(wt, v[k].w, a3);
        }
    }
    for (; j + 2 <= nTot; j += 2) {
        ull pr = lp[j + hi];
        float wt = __uint_as_float((unsigned)(pr >> 32));
        const float4 v = *(const float4*)(emb + (size_t)(unsigned)pr * DIM + cb);
        a0 = fmaf(wt, v.x, a0); a1 = fmaf(wt, v.y, a1);
        a2 = fmaf(wt, v.z, a2); a3 = fmaf(wt, v.w, a3);
    }
    if (j < nTot) {
        ull pr = lp[j];
        float wt = hi ? 0.0f : __uint_as_float((unsigned)(pr >> 32));
        const float4 v = *(const float4*)(emb + (size_t)(unsigned)pr * DIM + cb);
        a0 = fmaf(wt, v.x, a0); a1 = fmaf(wt, v.y, a1);
        a2 = fmaf(wt, v.z, a2); a3 = fmaf(wt, v.w, a3);
    }

    a0 += __shfl_xor(a0, 32);
    a1 += __shfl_xor(a1, 32);
    a2 += __shfl_xor(a2, 32);
    a3 += __shfl_xor(a3, 32);

    if (s < 32) {
        float* op = out + (size_t)tree * DIM + cb;
        *(float4*)op = make_float4(a0, a1, a2, a3);
    }
}

extern "C" void kernel_launch(void* const* d_in, const int* in_sizes, int n_in,
                              void* d_out, int out_size, void* d_ws, size_t ws_size,
                              hipStream_t stream) {
    const int*   tokens = (const int*)d_in[0];
    const void*  masks  = d_in[1];
    const float* emb    = (const float*)d_in[2];
    const float* cw     = (const float*)d_in[3];
    float*       out    = (float*)d_out;

    // Workspace: ts f32 (120 KB, padded to 128 KB) + fp16 table (7.68 MB).
    const size_t o_ts  = 0;
    const size_t o_e16 = 128 * 1024;
    const size_t need  = o_e16 + (size_t)VOCAB * DIM * 2;

    float*  ts  = (float*)((char*)d_ws + o_ts);
    __half* e16 = (__half*)((char*)d_ws + o_e16);

    const bool fp16path = (ws_size >= need);
    int ts_blocks = (VOCAB * 64 + 255) / 256;   // one wave per vocab row
    tokscore_kernel<<<ts_blocks, 256, 0, stream>>>(
        emb, cw, ts, fp16path ? (__half2*)e16 : (__half2*)nullptr);

    if (fp16path) {
        fused16_kernel<<<NUM_TREES / TPA, 256, 0, stream>>>(tokens, masks, ts,
                                                            e16, out);
    } else {
        fused_kernel<<<NUM_TREES / TPA, 256, 0, stream>>>(tokens, masks, ts,
                                                          emb, out);
    }
}

// Round 15
// 233.850 us; speedup vs baseline: 1.2098x; 1.0231x over previous
//
#include <hip/hip_runtime.h>
#include <hip/hip_fp16.h>
#include <math.h>

#define NUM_TREES 20000
#define MAX_DEPTH 8
#define MAX_SIZE  40
#define VOCAB     30000
#define DIM       128
#define TOT       (MAX_DEPTH * MAX_SIZE)       // 320 tokens per tree
#define NTILE     4                            // r15: 8->4 — halves sort VALU;
#define TILE_ROWS (VOCAB / NTILE)              // 7500 rows = 1.9 MB fp16 (the
                                               // L2-validated tile footprint)
#define TPA       4                            // trees per block (wave per tree)

typedef unsigned long long ull;

__device__ __forceinline__ double waveSumD(double v) {
    v += __shfl_xor(v, 32);
    v += __shfl_xor(v, 16);
    v += __shfl_xor(v, 8);
    v += __shfl_xor(v, 4);
    v += __shfl_xor(v, 2);
    v += __shfl_xor(v, 1);
    return v;
}

__device__ __forceinline__ float waveSumF(float v) {
    v += __shfl_xor(v, 32);
    v += __shfl_xor(v, 16);
    v += __shfl_xor(v, 8);
    v += __shfl_xor(v, 4);
    v += __shfl_xor(v, 2);
    v += __shfl_xor(v, 1);
    return v;
}

// One packed butterfly for three independent fp32 sums (ILP hides the
// per-step shuffle latency across the three chains).
__device__ __forceinline__ void waveSum3F(float& a, float& b, float& c) {
    #pragma unroll
    for (int m = 32; m >= 1; m >>= 1) {
        a += __shfl_xor(a, m);
        b += __shfl_xor(b, m);
        c += __shfl_xor(c, m);
    }
}

// masks may arrive as 1-byte bool or int32; probe word 0 (all-ones input:
// byte layout reads 0x01010101, int32 layout reads 0x00000001).
__device__ __forceinline__ int loadMask(const void* m, size_t idx, bool asByte) {
    return asByte ? (int)((const unsigned char*)m)[idx] : ((const int*)m)[idx];
}

// Phase 0 (fused): ts[v] = dot(embedding[v], cw) (fp64 reduce, f32 store)
// AND fp16 conversion of the row the wave already holds.
__global__ __launch_bounds__(256) void tokscore_kernel(
        const float* __restrict__ emb, const float* __restrict__ cw,
        float* __restrict__ ts, __half2* __restrict__ e16) {
    int row  = (blockIdx.x * blockDim.x + threadIdx.x) >> 6;
    int lane = threadIdx.x & 63;
    if (row >= VOCAB) return;
    float2 e2 = *(const float2*)(emb + (size_t)row * DIM + lane * 2);
    float2 w2 = *(const float2*)(cw + lane * 2);
    if (e16) e16[(size_t)row * 64 + lane] = __floats2half2_rn(e2.x, e2.y);
    double p = (double)e2.x * (double)w2.x + (double)e2.y * (double)w2.y;
    p = waveSumD(p);
    if (lane == 0) ts[row] = (float)p;
}

// Shared device body: fp32 recursion + ballot sort (validated round 12;
// absmax unchanged at 0.0078 — fp16 table dominates the error). NTILE=4
// this round: the counting sort was ~2x the recursion's VALU cost at
// NTILE=8 (two sweeps of 8x8 ballots); 8x4 halves it, and the 1.9 MB fp16
// tile matches the L2 footprint validated across rounds 4-12.
__device__ __forceinline__ int recursion_and_sort(
        const int* __restrict__ tokens, const void* __restrict__ masks,
        const float* __restrict__ ts, ull (*l_pair)[TOT],
        int w, int s, size_t base) {
    const bool mByte = (((const int*)masks)[0] != 1);
    const bool inS = s < MAX_SIZE;

    int   tok[MAX_DEPTH];
    float e[MAX_DEPTH];
    unsigned int valbit = 0, mskbit = 0;
    #pragma unroll
    for (int d = 0; d < MAX_DEPTH; ++d) {
        int t = -1, m = 0;
        if (inS) {
            t = tokens[base + d * MAX_SIZE + s];
            m = loadMask(masks, base + d * MAX_SIZE + s, mByte);
        }
        tok[d] = t < 0 ? 0 : t;
        e[d]   = inS ? ts[tok[d]] : 0.0f;
        if (inS && m != 0) mskbit |= 1u << d;
        if (inS && m != 0 && t >= 0) valbit |= 1u << d;
    }
    unsigned int childbit = 0;
    #pragma unroll
    for (int d = 0; d < MAX_DEPTH - 1; ++d) {
        ull bal = __ballot((mskbit >> (d + 1)) & 1u);
        int nc = (int)__popcll(bal);
        if (nc < 1) nc = 1;
        if (((valbit >> d) & 1u) && s < nc) childbit |= 1u << d;
    }

    float v7 = ((valbit >> 7) & 1u) ? 1.0f : 0.0f;
    float pw = waveSumF(e[7] * v7);

    float attnf[MAX_DEPTH - 1];
    float cArr[MAX_DEPTH - 1];
    #pragma unroll
    for (int d = MAX_DEPTH - 2; d >= 0; --d) {
        float gf = 1.0f / (1.0f + __expf(-e[d]));
        float cf = ((childbit >> d) & 1u) ? gf : 0.0f;   // gate*child
        float a  = fmaf(cf, pw, e[d]);
        float ex = ((valbit >> d) & 1u) ? __expf(a) : 0.0f;
        float s0 = ex;            // -> den
        float s1 = ex * cf;       // -> c * den
        float s2 = ex * e[d];     // -> (sum attn*e) * den
        waveSum3F(s0, s1, s2);
        float inv = 1.0f / s0;
        float c   = s1 * inv;
        pw = fmaf(c, pw, s2 * inv);
        attnf[d] = ex * inv;      // attn
        cArr[d]  = c;
    }
    float coef[MAX_DEPTH];
    float prefix = 1.0f;
    #pragma unroll
    for (int d = 0; d <= MAX_DEPTH - 2; ++d) {
        coef[d] = prefix * attnf[d];
        prefix *= cArr[d];
    }
    coef[MAX_DEPTH - 1] = prefix * v7;

    int tl[MAX_DEPTH];
    unsigned int nzbit = 0;
    #pragma unroll
    for (int d = 0; d < MAX_DEPTH; ++d) {
        tl[d] = tok[d] / TILE_ROWS;
        if (coef[d] != 0.0f) nzbit |= 1u << d;
    }
    const ull ltm = (1ull << s) - 1ull;

    int cnt[NTILE];
    #pragma unroll
    for (int t = 0; t < NTILE; ++t) cnt[t] = 0;
    #pragma unroll
    for (int d = 0; d < MAX_DEPTH; ++d) {
        bool nz = (nzbit >> d) & 1u;
        #pragma unroll
        for (int t = 0; t < NTILE; ++t)
            cnt[t] += (int)__popcll(__ballot(nz && tl[d] == t));
    }
    int hoff[NTILE + 1];
    hoff[0] = 0;
    #pragma unroll
    for (int t = 0; t < NTILE; ++t) hoff[t + 1] = hoff[t] + cnt[t];

    int ridx[NTILE];
    #pragma unroll
    for (int t = 0; t < NTILE; ++t) ridx[t] = hoff[t];
    #pragma unroll
    for (int d = 0; d < MAX_DEPTH; ++d) {
        bool nz = (nzbit >> d) & 1u;
        int slot = -1;
        #pragma unroll
        for (int t = 0; t < NTILE; ++t) {
            ull m = __ballot(nz && tl[d] == t);
            if (nz && tl[d] == t) slot = ridx[t] + (int)__popcll(m & ltm);
            ridx[t] += (int)__popcll(m);
        }
        if (slot >= 0)
            l_pair[w][slot] =
                ((ull)__float_as_uint(coef[d]) << 32) | (ull)(unsigned)tok[d];
    }
    return __builtin_amdgcn_readfirstlane(hoff[NTILE]);
}

// Fused kernel, fp16 quarter-wave gather (validated rounds 11-14): lanes
// 0-15 row j, 16-31 j+1, 32-47 j+2, 48-63 j+3; each lane loads uint4 = 8
// halves; 64 lanes x 16B = 1KB = FOUR fp16 rows per instruction; 8 loads in
// flight. (256,4): validated no-spill config across rounds 7-12 (tighter
// bounds spill — rounds 6/9/13; (256,5) r14: no spill but no occupancy
// change either — HW occupancy follows actual VGPR, 44 -> 16 waves/CU).
__global__ __launch_bounds__(256, 4) void fused16_kernel(
        const int* __restrict__ tokens, const void* __restrict__ masks,
        const float* __restrict__ ts, const __half* __restrict__ e16,
        float* __restrict__ out) {
    __shared__ ull l_pair[TPA][TOT];   // 10 KB, tile-sorted pairs per tree

    const int tid  = threadIdx.x;
    const int w    = tid >> 6;
    const int s    = tid & 63;
    const int tree = blockIdx.x * TPA + w;
    const size_t base = (size_t)tree * TOT;

    const int nTot = recursion_and_sort(tokens, masks, ts, l_pair, w, s, base);

    // Gather (wave-local LDS, no barrier needed — validated rounds 5-14).
    const int q  = s >> 4;                 // quarter id: row offset 0..3
    const int cb = (s & 15) << 3;          // column base: 8 elements per lane
    const ull* lp = &l_pair[w][0];
    float a0 = 0.f, a1 = 0.f, a2 = 0.f, a3 = 0.f;
    float a4 = 0.f, a5 = 0.f, a6 = 0.f, a7 = 0.f;

    int j = 0;
    for (; j + 32 <= nTot; j += 32) {      // 32 rows = 8 uint4 loads in flight
        ull pr[8];
        #pragma unroll
        for (int k = 0; k < 8; ++k) pr[k] = lp[j + 4 * k + q];
        uint4 v[8];
        #pragma unroll
        for (int k = 0; k < 8; ++k)
            v[k] = *(const uint4*)(e16 + (size_t)(unsigned)pr[k] * DIM + cb);
        __builtin_amdgcn_sched_barrier(0);  // all 8 loads issued before use
        #pragma unroll
        for (int k = 0; k < 8; ++k) {
            float wt = __uint_as_float((unsigned)(pr[k] >> 32));
            float2 f0 = __half22float2(*(const __half2*)&v[k].x);
            float2 f1 = __half22float2(*(const __half2*)&v[k].y);
            float2 f2 = __half22float2(*(const __half2*)&v[k].z);
            float2 f3 = __half22float2(*(const __half2*)&v[k].w);
            a0 = fmaf(wt, f0.x, a0); a1 = fmaf(wt, f0.y, a1);
            a2 = fmaf(wt, f1.x, a2); a3 = fmaf(wt, f1.y, a3);
            a4 = fmaf(wt, f2.x, a4); a5 = fmaf(wt, f2.y, a5);
            a6 = fmaf(wt, f3.x, a6); a7 = fmaf(wt, f3.y, a7);
        }
    }
    for (; j + 4 <= nTot; j += 4) {        // 4 rows per step
        ull pr = lp[j + q];
        float wt = __uint_as_float((unsigned)(pr >> 32));
        uint4 v = *(const uint4*)(e16 + (size_t)(unsigned)pr * DIM + cb);
        float2 f0 = __half22float2(*(const __half2*)&v.x);
        float2 f1 = __half22float2(*(const __half2*)&v.y);
        float2 f2 = __half22float2(*(const __half2*)&v.z);
        float2 f3 = __half22float2(*(const __half2*)&v.w);
        a0 = fmaf(wt, f0.x, a0); a1 = fmaf(wt, f0.y, a1);
        a2 = fmaf(wt, f1.x, a2); a3 = fmaf(wt, f1.y, a3);
        a4 = fmaf(wt, f2.x, a4); a5 = fmaf(wt, f2.y, a5);
        a6 = fmaf(wt, f3.x, a6); a7 = fmaf(wt, f3.y, a7);
    }
    if (j < nTot) {                        // 1-3 leftover rows
        int rem = nTot - j;
        ull pr = lp[j + (q < rem ? q : 0)];            // inactive quarters re-
        float wt = (q < rem) ? __uint_as_float((unsigned)(pr >> 32)) : 0.0f;
        uint4 v = *(const uint4*)(e16 + (size_t)(unsigned)pr * DIM + cb);
        float2 f0 = __half22float2(*(const __half2*)&v.x); // read row j, wt=0
        float2 f1 = __half22float2(*(const __half2*)&v.y);
        float2 f2 = __half22float2(*(const __half2*)&v.z);
        float2 f3 = __half22float2(*(const __half2*)&v.w);
        a0 = fmaf(wt, f0.x, a0); a1 = fmaf(wt, f0.y, a1);
        a2 = fmaf(wt, f1.x, a2); a3 = fmaf(wt, f1.y, a3);
        a4 = fmaf(wt, f2.x, a4); a5 = fmaf(wt, f2.y, a5);
        a6 = fmaf(wt, f3.x, a6); a7 = fmaf(wt, f3.y, a7);
    }

    // Reduce across the 4 quarters (lanes with equal (s&15) share columns).
    a0 += __shfl_xor(a0, 16); a1 += __shfl_xor(a1, 16);
    a2 += __shfl_xor(a2, 16); a3 += __shfl_xor(a3, 16);
    a4 += __shfl_xor(a4, 16); a5 += __shfl_xor(a5, 16);
    a6 += __shfl_xor(a6, 16); a7 += __shfl_xor(a7, 16);
    a0 += __shfl_xor(a0, 32); a1 += __shfl_xor(a1, 32);
    a2 += __shfl_xor(a2, 32); a3 += __shfl_xor(a3, 32);
    a4 += __shfl_xor(a4, 32); a5 += __shfl_xor(a5, 32);
    a6 += __shfl_xor(a6, 32); a7 += __shfl_xor(a7, 32);

    if (s < 16) {
        float* op = out + (size_t)tree * DIM + cb;
        *(float4*)op       = make_float4(a0, a1, a2, a3);
        *(float4*)(op + 4) = make_float4(a4, a5, a6, a7);
    }
}

// Fallback: fp32-table fused gather (validated rounds 7-8) for tiny
// workspaces.
__global__ __launch_bounds__(256, 4) void fused_kernel(
        const int* __restrict__ tokens, const void* __restrict__ masks,
        const float* __restrict__ ts, const float* __restrict__ emb,
        float* __restrict__ out) {
    __shared__ ull l_pair[TPA][TOT];

    const int tid  = threadIdx.x;
    const int w    = tid >> 6;
    const int s    = tid & 63;
    const int tree = blockIdx.x * TPA + w;
    const size_t base = (size_t)tree * TOT;

    const int nTot = recursion_and_sort(tokens, masks, ts, l_pair, w, s, base);

    const int hi = (s >= 32) ? 1 : 0;
    const int cb = (s & 31) << 2;
    const ull* lp = &l_pair[w][0];
    float a0 = 0.0f, a1 = 0.0f, a2 = 0.0f, a3 = 0.0f;

    int j = 0;
    for (; j + 8 <= nTot; j += 8) {
        ull pr[4];
        #pragma unroll
        for (int k = 0; k < 4; ++k) pr[k] = lp[j + 2 * k + hi];
        float4 v[4];
        #pragma unroll
        for (int k = 0; k < 4; ++k)
            v[k] = *(const float4*)(emb + (size_t)(unsigned)pr[k] * DIM + cb);
        #pragma unroll
        for (int k = 0; k < 4; ++k) {
            float wt = __uint_as_float((unsigned)(pr[k] >> 32));
            a0 = fmaf(wt, v[k].x, a0); a1 = fmaf(wt, v[k].y, a1);
            a2 = fmaf(wt, v[k].z, a2); a3 = fmaf(wt, v[k].w, a3);
        }
    }
    for (; j + 2 <= nTot; j += 2) {
        ull pr = lp[j + hi];
        float wt = __uint_as_float((unsigned)(pr >> 32));
        const float4 v = *(const float4*)(emb + (size_t)(unsigned)pr * DIM + cb);
        a0 = fmaf(wt, v.x, a0); a1 = fmaf(wt, v.y, a1);
        a2 = fmaf(wt, v.z, a2); a3 = fmaf(wt, v.w, a3);
    }
    if (j < nTot) {
        ull pr = lp[j];
        float wt = hi ? 0.0f : __uint_as_float((unsigned)(pr >> 32));
        const float4 v = *(const float4*)(emb + (size_t)(unsigned)pr * DIM + cb);
        a0 = fmaf(wt, v.x, a0); a1 = fmaf(wt, v.y, a1);
        a2 = fmaf(wt, v.z, a2); a3 = fmaf(wt, v.w, a3);
    }

    a0 += __shfl_xor(a0, 32);
    a1 += __shfl_xor(a1, 32);
    a2 += __shfl_xor(a2, 32);
    a3 += __shfl_xor(a3, 32);

    if (s < 32) {
        float* op = out + (size_t)tree * DIM + cb;
        *(float4*)op = make_float4(a0, a1, a2, a3);
    }
}

extern "C" void kernel_launch(void* const* d_in, const int* in_sizes, int n_in,
                              void* d_out, int out_size, void* d_ws, size_t ws_size,
                              hipStream_t stream) {
    const int*   tokens = (const int*)d_in[0];
    const void*  masks  = d_in[1];
    const float* emb    = (const float*)d_in[2];
    const float* cw     = (const float*)d_in[3];
    float*       out    = (float*)d_out;

    // Workspace: ts f32 (120 KB, padded to 128 KB) + fp16 table (7.68 MB).
    const size_t o_ts  = 0;
    const size_t o_e16 = 128 * 1024;
    const size_t need  = o_e16 + (size_t)VOCAB * DIM * 2;

    float*  ts  = (float*)((char*)d_ws + o_ts);
    __half* e16 = (__half*)((char*)d_ws + o_e16);

    const bool fp16path = (ws_size >= need);
    int ts_blocks = (VOCAB * 64 + 255) / 256;   // one wave per vocab row
    tokscore_kernel<<<ts_blocks, 256, 0, stream>>>(
        emb, cw, ts, fp16path ? (__half2*)e16 : (__half2*)nullptr);

    if (fp16path) {
        fused16_kernel<<<NUM_TREES / TPA, 256, 0, stream>>>(tokens, masks, ts,
                                                            e16, out);
    } else {
        fused_kernel<<<NUM_TREES / TPA, 256, 0, stream>>>(tokens, masks, ts,
                                                          emb, out);
    }
}